// Round 1
// baseline (1080.318 us; speedup 1.0000x reference)
//
#include <hip/hip_runtime.h>
#include <math.h>

#define BB 32
#define TT 1024
#define HH 128

// Kernel A: gather embedding rows, normalize to unit length, compute lambda.
// One wave (64 lanes) per row; 4 waves per block.
__global__ __launch_bounds__(256)
void gather_norm(const int* __restrict__ seq,
                 const float* __restrict__ embd,
                 const float* __restrict__ lam_w,
                 const float* __restrict__ lam_b,
                 float* __restrict__ xhat,
                 float* __restrict__ lam) {
    int row  = blockIdx.x * 4 + (threadIdx.x >> 6);
    int lane = threadIdx.x & 63;
    if (row >= BB * TT) return;
    int idx = seq[row];
    const float2* src = (const float2*)(embd + (size_t)idx * HH);
    float2 v = src[lane];                       // elements 2*lane, 2*lane+1
    float2 w = ((const float2*)lam_w)[lane];
    float ss = v.x * v.x + v.y * v.y;
    float dw = v.x * w.x + v.y * w.y;
    #pragma unroll
    for (int off = 32; off > 0; off >>= 1) {
        ss += __shfl_down(ss, off);
        dw += __shfl_down(dw, off);
    }
    ss = __shfl(ss, 0);
    dw = __shfl(dw, 0);
    float inv = 1.0f / sqrtf(ss);
    float2 o; o.x = v.x * inv; o.y = v.y * inv;
    ((float2*)(xhat + (size_t)row * HH))[lane] = o;
    if (lane == 0) lam[row] = expf(dw + lam_b[0]);
}

// Kernel B: one block per (b, t). Thread i owns s in [4i, 4i+4).
__global__ __launch_bounds__(256)
void row_kernel(const float* __restrict__ xhat,
                const float* __restrict__ lam,
                const float* __restrict__ y,
                float* __restrict__ out) {
    int b = blockIdx.x / TT;
    int t = blockIdx.x % TT;
    int tid = threadIdx.x;

    __shared__ float xt[HH];
    __shared__ float totals[256];
    __shared__ float rw[4], ry[4];

    const float* xrow = xhat + ((size_t)(b * TT + t)) * HH;
    if (tid < 32) ((float4*)xt)[tid] = ((const float4*)xrow)[tid];
    __syncthreads();

    float lam_t = lam[b * TT + t];

    // --- similarity for my 4 s-values ---
    float simv[4];
    int s0 = tid * 4;
    #pragma unroll
    for (int j = 0; j < 4; j++) {
        int s = s0 + j;
        float sv = 0.0f;
        if (s < t) {
            const float4* xs = (const float4*)(xhat + ((size_t)(b * TT + s)) * HH);
            float dot = 0.0f;
            #pragma unroll
            for (int k = 0; k < HH / 4; k++) {
                float4 a = xs[k];
                float4 c = ((const float4*)xt)[k];
                dot += a.x * c.x + a.y * c.y + a.z * c.z + a.w * c.w;
            }
            sv = (dot + 1.0f) * 0.5f;   // strictly-lower-tri entries only
        }
        simv[j] = sv;
    }

    // --- local suffix sums within chunk ---
    float lsuf[4];
    lsuf[3] = simv[3];
    lsuf[2] = simv[2] + lsuf[3];
    lsuf[1] = simv[1] + lsuf[2];
    lsuf[0] = simv[0] + lsuf[1];
    float my_total = lsuf[0];
    totals[tid] = my_total;
    __syncthreads();

    // --- block-wide inclusive suffix scan (Hillis-Steele, reversed) ---
    #pragma unroll
    for (int off = 1; off < 256; off <<= 1) {
        float v = totals[tid];
        if (tid + off < 256) v += totals[tid + off];
        __syncthreads();
        totals[tid] = v;
        __syncthreads();
    }
    float excl = totals[tid] - my_total;   // sum over threads > tid

    // --- weights + weighted sum of y ---
    float wsum = 0.0f, wy = 0.0f;
    #pragma unroll
    for (int j = 0; j < 4; j++) {
        int s = s0 + j;
        float delta = lsuf[j] + excl;
        float wgt = simv[j] * expf(-lam_t * delta);  // simv==0 for s>=t
        wsum += wgt;
        if (s < t) wy += wgt * y[b * TT + s];
    }
    // wave reduce
    #pragma unroll
    for (int off = 32; off > 0; off >>= 1) {
        wsum += __shfl_down(wsum, off);
        wy   += __shfl_down(wy, off);
    }
    int wid = tid >> 6;
    if ((tid & 63) == 0) { rw[wid] = wsum; ry[wid] = wy; }
    __syncthreads();
    if (tid == 0) {
        float W = rw[0] + rw[1] + rw[2] + rw[3];
        float Y = ry[0] + ry[1] + ry[2] + ry[3];
        float v = Y / (W + 1e-6f);
        v = fminf(fmaxf(v, 0.01f), 0.99f);
        out[b * TT + t] = v;
    }
}

extern "C" void kernel_launch(void* const* d_in, const int* in_sizes, int n_in,
                              void* d_out, int out_size, void* d_ws, size_t ws_size,
                              hipStream_t stream) {
    const float* y     = (const float*)d_in[0];
    const int*   seq   = (const int*)  d_in[1];
    const float* embd  = (const float*)d_in[2];
    const float* lam_w = (const float*)d_in[3];
    const float* lam_b = (const float*)d_in[4];
    float* out  = (float*)d_out;
    float* xhat = (float*)d_ws;                       // B*T*H floats = 16 MB
    float* lam  = xhat + (size_t)BB * TT * HH;        // B*T floats

    gather_norm<<<BB * TT / 4, 256, 0, stream>>>(seq, embd, lam_w, lam_b, xhat, lam);
    row_kernel<<<BB * TT, 256, 0, stream>>>(xhat, lam, y, out);
}

// Round 2
// 156.497 us; speedup vs baseline: 6.9031x; 6.9031x over previous
//
#include <hip/hip_runtime.h>
#include <math.h>

#define BB 32
#define TT 1024
#define HH 128

typedef __attribute__((ext_vector_type(8))) short short8;
typedef __attribute__((ext_vector_type(4))) float floatx4;

__device__ __forceinline__ unsigned short f2bf(float f) {
    unsigned u = __float_as_uint(f);
    u += 0x7fffu + ((u >> 16) & 1u);
    return (unsigned short)(u >> 16);
}

// Kernel A: gather embedding rows, normalize to unit length (store bf16),
// compute lambda = exp(x_raw . lam_w + lam_b). One wave per row.
__global__ __launch_bounds__(256)
void gather_norm(const int* __restrict__ seq,
                 const float* __restrict__ embd,
                 const float* __restrict__ lam_w,
                 const float* __restrict__ lam_b,
                 unsigned short* __restrict__ xbf,
                 float* __restrict__ lam) {
    int row  = blockIdx.x * 4 + (threadIdx.x >> 6);
    int lane = threadIdx.x & 63;
    int idx = seq[row];
    float2 v = ((const float2*)(embd + (size_t)idx * HH))[lane];
    float2 w = ((const float2*)lam_w)[lane];
    float ss = v.x * v.x + v.y * v.y;
    float dw = v.x * w.x + v.y * w.y;
    #pragma unroll
    for (int off = 32; off > 0; off >>= 1) {
        ss += __shfl_down(ss, off);
        dw += __shfl_down(dw, off);
    }
    ss = __shfl(ss, 0);
    dw = __shfl(dw, 0);
    float inv = 1.0f / sqrtf(ss);
    unsigned bx = f2bf(v.x * inv);
    unsigned by = f2bf(v.y * inv);
    ((unsigned*)xbf)[(size_t)row * 64 + lane] = bx | (by << 16);
    if (lane == 0) lam[row] = expf(dw + lam_b[0]);
}

// Kernel B: flash-style streaming over s-tiles (high->low) with MFMA.
// Each wave owns 16 t-values (ttile = wave*16 + slot for load balance).
// D = Xs * Xq^T gives D[m=s_local][n=t_local]:
//   n = lane&15 (t), m = quad*4 + reg (s)  [C/D layout, m89/m91]
// A/B fragments: X[row = lane&15][k = quad*8 + j]  (j = 0..7 within short8)
__global__ __launch_bounds__(256)
void sim_kernel(const unsigned short* __restrict__ xbf,
                const float* __restrict__ lam,
                const float* __restrict__ y,
                float* __restrict__ out) {
    const int b    = blockIdx.x >> 4;
    const int slot = blockIdx.x & 15;
    const int wave = threadIdx.x >> 6;
    const int lane = threadIdx.x & 63;
    const int tl   = lane & 15;
    const int quad = lane >> 4;

    const int ttile = wave * 16 + slot;          // 0..63
    const int t     = ttile * 16 + tl;
    const size_t rowbase = (size_t)b * TT;

    const float lam_t = lam[rowbase + t];
    const float* yb = y + rowbase;

    // preload Xq fragments (B operand), 4 K-steps of 32
    short8 bq[4];
    const short8* qrow = (const short8*)(xbf + (rowbase + t) * HH);
    #pragma unroll
    for (int kk = 0; kk < 4; kk++) bq[kk] = qrow[kk * 4 + quad];

    float wsum = 0.f, wy = 0.f, carry = 0.f;

    for (int st = ttile; st >= 0; --st) {
        const int s_base = st << 4;
        const short8* arow =
            (const short8*)(xbf + (rowbase + s_base + tl) * HH);
        floatx4 acc = {0.f, 0.f, 0.f, 0.f};
        #pragma unroll
        for (int kk = 0; kk < 4; kk++) {
            short8 af = arow[kk * 4 + quad];
            acc = __builtin_amdgcn_mfma_f32_16x16x32_bf16(af, bq[kk], acc, 0, 0, 0);
        }

        const int s0g = s_base + quad * 4;
        float v0 = (s0g + 0 < t) ? (acc[0] + 1.f) * 0.5f : 0.f;
        float v1 = (s0g + 1 < t) ? (acc[1] + 1.f) * 0.5f : 0.f;
        float v2 = (s0g + 2 < t) ? (acc[2] + 1.f) * 0.5f : 0.f;
        float v3 = (s0g + 3 < t) ? (acc[3] + 1.f) * 0.5f : 0.f;

        // in-lane inclusive suffix over the 4 s values
        float suf3 = v3;
        float suf2 = v2 + suf3;
        float suf1 = v1 + suf2;
        float suf0 = v0 + suf1;
        float tot = suf0;

        // cross-quad totals (lanes tl, tl+16, tl+32, tl+48 share t)
        float q0 = __shfl(tot, tl);
        float q1 = __shfl(tot, tl + 16);
        float q2 = __shfl(tot, tl + 32);
        float q3 = __shfl(tot, tl + 48);
        float higher = (quad < 1 ? q1 : 0.f) + (quad < 2 ? q2 : 0.f) +
                       (quad < 3 ? q3 : 0.f);
        float base = higher + carry;
        carry += (q0 + q1) + (q2 + q3);

        float4 yv = ((const float4*)(yb + s_base))[quad];
        float w0 = v0 * __expf(-lam_t * (suf0 + base));
        float w1 = v1 * __expf(-lam_t * (suf1 + base));
        float w2 = v2 * __expf(-lam_t * (suf2 + base));
        float w3 = v3 * __expf(-lam_t * (suf3 + base));
        wsum += (w0 + w1) + (w2 + w3);
        wy   += w0 * yv.x + w1 * yv.y + w2 * yv.z + w3 * yv.w;
    }

    // reduce across quads for each t
    float Wt = __shfl(wsum, tl) + __shfl(wsum, tl + 16) +
               __shfl(wsum, tl + 32) + __shfl(wsum, tl + 48);
    float Yt = __shfl(wy, tl) + __shfl(wy, tl + 16) +
               __shfl(wy, tl + 32) + __shfl(wy, tl + 48);
    if (quad == 0) {
        float r = Yt / (Wt + 1e-6f);
        out[rowbase + t] = fminf(fmaxf(r, 0.01f), 0.99f);
    }
}

extern "C" void kernel_launch(void* const* d_in, const int* in_sizes, int n_in,
                              void* d_out, int out_size, void* d_ws, size_t ws_size,
                              hipStream_t stream) {
    const float* y     = (const float*)d_in[0];
    const int*   seq   = (const int*)  d_in[1];
    const float* embd  = (const float*)d_in[2];
    const float* lam_w = (const float*)d_in[3];
    const float* lam_b = (const float*)d_in[4];
    float* out = (float*)d_out;

    unsigned short* xbf = (unsigned short*)d_ws;            // B*T*H bf16 = 8 MB
    float* lam = (float*)(xbf + (size_t)BB * TT * HH);      // B*T floats

    gather_norm<<<BB * TT / 4, 256, 0, stream>>>(seq, embd, lam_w, lam_b, xbf, lam);
    sim_kernel<<<BB * 16, 256, 0, stream>>>(xbf, lam, y, out);
}

// Round 3
// 121.403 us; speedup vs baseline: 8.8986x; 1.2891x over previous
//
#include <hip/hip_runtime.h>
#include <math.h>

#define BB 32
#define TT 1024
#define HH 128

typedef __attribute__((ext_vector_type(8))) short short8;
typedef __attribute__((ext_vector_type(4))) float floatx4;

__device__ __forceinline__ unsigned short f2bf(float f) {
    unsigned u = __float_as_uint(f);
    u += 0x7fffu + ((u >> 16) & 1u);
    return (unsigned short)(u >> 16);
}

// Kernel A: gather embedding rows, normalize to unit length (store bf16),
// compute lambda = exp(x_raw . lam_w + lam_b). One wave per row.
__global__ __launch_bounds__(256)
void gather_norm(const int* __restrict__ seq,
                 const float* __restrict__ embd,
                 const float* __restrict__ lam_w,
                 const float* __restrict__ lam_b,
                 unsigned short* __restrict__ xbf,
                 float* __restrict__ lam) {
    int row  = blockIdx.x * 4 + (threadIdx.x >> 6);
    int lane = threadIdx.x & 63;
    int idx = seq[row];
    float2 v = ((const float2*)(embd + (size_t)idx * HH))[lane];
    float2 w = ((const float2*)lam_w)[lane];
    float ss = v.x * v.x + v.y * v.y;
    float dw = v.x * w.x + v.y * w.y;
    #pragma unroll
    for (int off = 32; off > 0; off >>= 1) {
        ss += __shfl_down(ss, off);
        dw += __shfl_down(dw, off);
    }
    ss = __shfl(ss, 0);
    dw = __shfl(dw, 0);
    float inv = 1.0f / sqrtf(ss);
    unsigned bx = f2bf(v.x * inv);
    unsigned by = f2bf(v.y * inv);
    ((unsigned*)xbf)[(size_t)row * 64 + lane] = bx | (by << 16);
    if (lane == 0) lam[row] = expf(dw + lam_b[0]);
}

// Kernel B: one block per (b, t-tile). 4 waves split the s-range [0, tt]
// into contiguous chunks (wave 3 = highest s). Each wave streams its chunk
// high->low with MFMA (D[m=s_local=quad*4+reg][n=t_local=lane&15]),
// producing per-t partials (W, Y, T=sim total). Chunks are merged with the
// associative rescale: lower chunk scaled by exp(-lam * sum of T above).
__global__ __launch_bounds__(256)
void sim_kernel(const unsigned short* __restrict__ xbf,
                const float* __restrict__ lam,
                const float* __restrict__ y,
                float* __restrict__ out) {
    const int b    = blockIdx.x & 31;
    const int tt   = 63 - (blockIdx.x >> 5);     // largest tiles first
    const int tid  = threadIdx.x;
    const int wave = tid >> 6;
    const int lane = tid & 63;
    const int tl   = lane & 15;
    const int quad = lane >> 4;

    const int t = tt * 16 + tl;
    const size_t rowbase = (size_t)b * TT;
    const float lam_t = lam[rowbase + t];
    const float* yb = y + rowbase;

    __shared__ float Wc[4][16], Yc[4][16], Tc[4][16];

    // preload Xq fragments (B operand), 4 K-steps of 32
    short8 bq[4];
    const short8* qrow = (const short8*)(xbf + (rowbase + t) * HH);
    #pragma unroll
    for (int kk = 0; kk < 4; kk++) bq[kk] = qrow[kk * 4 + quad];

    // my chunk of s-tiles: [start, end)
    const int n    = tt + 1;
    const int base = n >> 2, rem = n & 3;
    const int cnt   = base + (wave < rem ? 1 : 0);
    const int start = wave * base + (wave < rem ? wave : rem);
    const int end   = start + cnt;

    float wsum = 0.f, wy = 0.f, carry = 0.f;

    for (int st = end - 1; st >= start; --st) {
        const int s_base = st << 4;
        const short8* arow =
            (const short8*)(xbf + (rowbase + s_base + tl) * HH);
        floatx4 acc = {0.f, 0.f, 0.f, 0.f};
        #pragma unroll
        for (int kk = 0; kk < 4; kk++) {
            short8 af = arow[kk * 4 + quad];
            acc = __builtin_amdgcn_mfma_f32_16x16x32_bf16(af, bq[kk], acc, 0, 0, 0);
        }

        const int s0g = s_base + quad * 4;
        float v0 = (s0g + 0 < t) ? (acc[0] + 1.f) * 0.5f : 0.f;
        float v1 = (s0g + 1 < t) ? (acc[1] + 1.f) * 0.5f : 0.f;
        float v2 = (s0g + 2 < t) ? (acc[2] + 1.f) * 0.5f : 0.f;
        float v3 = (s0g + 3 < t) ? (acc[3] + 1.f) * 0.5f : 0.f;

        // in-lane inclusive suffix over the 4 s values
        float suf3 = v3;
        float suf2 = v2 + suf3;
        float suf1 = v1 + suf2;
        float suf0 = v0 + suf1;
        float tot = suf0;

        // cross-quad totals (lanes tl, tl+16, tl+32, tl+48 share t)
        float q0 = __shfl(tot, tl);
        float q1 = __shfl(tot, tl + 16);
        float q2 = __shfl(tot, tl + 32);
        float q3 = __shfl(tot, tl + 48);
        float higher = (quad < 1 ? q1 : 0.f) + (quad < 2 ? q2 : 0.f) +
                       (quad < 3 ? q3 : 0.f);
        float dbase = higher + carry;
        carry += (q0 + q1) + (q2 + q3);

        float4 yv = ((const float4*)(yb + s_base))[quad];
        float w0 = v0 * __expf(-lam_t * (suf0 + dbase));
        float w1 = v1 * __expf(-lam_t * (suf1 + dbase));
        float w2 = v2 * __expf(-lam_t * (suf2 + dbase));
        float w3 = v3 * __expf(-lam_t * (suf3 + dbase));
        wsum += (w0 + w1) + (w2 + w3);
        wy   += w0 * yv.x + w1 * yv.y + w2 * yv.z + w3 * yv.w;
    }

    // reduce across quads for each t, store per-wave partials
    float Wt = __shfl(wsum, tl) + __shfl(wsum, tl + 16) +
               __shfl(wsum, tl + 32) + __shfl(wsum, tl + 48);
    float Yt = __shfl(wy, tl) + __shfl(wy, tl + 16) +
               __shfl(wy, tl + 32) + __shfl(wy, tl + 48);
    float Tt = __shfl(carry, tl) + 0.f;  // carry already summed across quads
    if (quad == 0) {
        Wc[wave][tl] = Wt;
        Yc[wave][tl] = Yt;
        Tc[wave][tl] = Tt;
    }
    __syncthreads();

    // merge the 4 chunks (wave 3 = highest s, needs no rescale)
    if (tid < 16) {
        float lt = lam[rowbase + tt * 16 + tid];
        float A = 0.f, W = 0.f, Y = 0.f;
        #pragma unroll
        for (int c = 3; c >= 0; --c) {
            float sc = __expf(-lt * A);
            W += Wc[c][tid] * sc;
            Y += Yc[c][tid] * sc;
            A += Tc[c][tid];
        }
        float r = Y / (W + 1e-6f);
        out[rowbase + tt * 16 + tid] = fminf(fmaxf(r, 0.01f), 0.99f);
    }
}

extern "C" void kernel_launch(void* const* d_in, const int* in_sizes, int n_in,
                              void* d_out, int out_size, void* d_ws, size_t ws_size,
                              hipStream_t stream) {
    const float* y     = (const float*)d_in[0];
    const int*   seq   = (const int*)  d_in[1];
    const float* embd  = (const float*)d_in[2];
    const float* lam_w = (const float*)d_in[3];
    const float* lam_b = (const float*)d_in[4];
    float* out = (float*)d_out;

    unsigned short* xbf = (unsigned short*)d_ws;            // B*T*H bf16 = 8 MB
    float* lam = (float*)(xbf + (size_t)BB * TT * HH);      // B*T floats

    gather_norm<<<BB * TT / 4, 256, 0, stream>>>(seq, embd, lam_w, lam_b, xbf, lam);
    sim_kernel<<<BB * 64, 256, 0, stream>>>(xbf, lam, y, out);
}

// Round 4
// 117.415 us; speedup vs baseline: 9.2009x; 1.0340x over previous
//
#include <hip/hip_runtime.h>
#include <math.h>

#define BB 32
#define TT 1024
#define HH 128

typedef __attribute__((ext_vector_type(8))) short short8;
typedef __attribute__((ext_vector_type(4))) float floatx4;

__device__ __forceinline__ unsigned short f2bf(float f) {
    unsigned u = __float_as_uint(f);
    u += 0x7fffu + ((u >> 16) & 1u);
    return (unsigned short)(u >> 16);
}

// Kernel A: gather embedding rows, normalize (store bf16), compute lambda.
// 32 lanes per row (float4 loads), 2 rows per wave, 8 rows per block.
__global__ __launch_bounds__(256)
void gather_norm(const int* __restrict__ seq,
                 const float* __restrict__ embd,
                 const float* __restrict__ lam_w,
                 const float* __restrict__ lam_b,
                 unsigned short* __restrict__ xbf,
                 float* __restrict__ lam) {
    const int lane = threadIdx.x & 63;
    const int half = lane >> 5;
    const int l32  = lane & 31;
    const int row  = blockIdx.x * 8 + (threadIdx.x >> 6) * 2 + half;
    const int idx  = seq[row];
    float4 v = ((const float4*)(embd + (size_t)idx * HH))[l32];
    float4 w = ((const float4*)lam_w)[l32];
    float ss = v.x * v.x + v.y * v.y + v.z * v.z + v.w * v.w;
    float dw = v.x * w.x + v.y * w.y + v.z * w.z + v.w * w.w;
    #pragma unroll
    for (int off = 16; off > 0; off >>= 1) {
        ss += __shfl_xor(ss, off);
        dw += __shfl_xor(dw, off);
    }
    float inv = 1.0f / sqrtf(ss);
    unsigned b0 = f2bf(v.x * inv), b1 = f2bf(v.y * inv);
    unsigned b2 = f2bf(v.z * inv), b3 = f2bf(v.w * inv);
    uint2 o; o.x = b0 | (b1 << 16); o.y = b2 | (b3 << 16);
    ((uint2*)(xbf + (size_t)row * HH))[l32] = o;
    if (l32 == 0) lam[row] = expf(dw + lam_b[0]);
}

// Kernel B: one block per (b, t-tile); 4 waves split s-range into contiguous
// chunks (wave 3 = highest s). Chunk processed in sub-batches of 4 s-tiles:
//   phase A (independent across tiles): MFMA sims -> regs, per-tile totals,
//            cross-quad exchange
//   suffix over the 4 tile totals (the only serial coupling, 1 per 4 tiles)
//   phase B (independent): exp/weight/accumulate
// Chunks merged with the associative rescale exp(-lam * totals-above).
__global__ __launch_bounds__(256)
void sim_kernel(const unsigned short* __restrict__ xbf,
                const float* __restrict__ lam,
                const float* __restrict__ y,
                float* __restrict__ out) {
    const int b    = blockIdx.x & 31;
    const int tt   = 63 - (blockIdx.x >> 5);     // largest tiles first
    const int tid  = threadIdx.x;
    const int wave = tid >> 6;
    const int lane = tid & 63;
    const int tl   = lane & 15;
    const int quad = lane >> 4;

    const int t = tt * 16 + tl;
    const size_t rowbase = (size_t)b * TT;
    const float lam_t = lam[rowbase + t];
    const float* yb = y + rowbase;

    __shared__ float Wc[4][16], Yc[4][16], Tc[4][16];

    // preload Xq fragments (B operand), 4 K-steps of 32
    short8 bq[4];
    const short8* qrow = (const short8*)(xbf + (rowbase + t) * HH);
    #pragma unroll
    for (int kk = 0; kk < 4; kk++) bq[kk] = qrow[kk * 4 + quad];

    // my chunk of s-tiles: [start, start+cnt)
    const int n    = tt + 1;
    const int base = n >> 2, rem = n & 3;
    const int cnt   = base + (wave < rem ? 1 : 0);
    const int start = wave * base + (wave < rem ? wave : rem);

    float wsum = 0.f, wy = 0.f, run = 0.f;   // run = sim totals of tiles above

    const int nsb = (cnt + 3) >> 2;
    for (int sb = nsb - 1; sb >= 0; --sb) {
        float vv[4][4];
        float tT[4], hq[4];

        // ---- phase A: sims + per-tile totals (independent across tiles) ----
        #pragma unroll
        for (int j = 0; j < 4; j++) {
            const int i = sb * 4 + j;
            float v0 = 0.f, v1 = 0.f, v2 = 0.f, v3 = 0.f;
            if (i < cnt) {
                const int s_base = (start + i) << 4;
                const short8* arow =
                    (const short8*)(xbf + (rowbase + s_base + tl) * HH);
                floatx4 acc = {0.f, 0.f, 0.f, 0.f};
                #pragma unroll
                for (int kk = 0; kk < 4; kk++) {
                    short8 af = arow[kk * 4 + quad];
                    acc = __builtin_amdgcn_mfma_f32_16x16x32_bf16(af, bq[kk], acc, 0, 0, 0);
                }
                const int s0g = s_base + quad * 4;
                v0 = (s0g + 0 < t) ? (acc[0] + 1.f) * 0.5f : 0.f;
                v1 = (s0g + 1 < t) ? (acc[1] + 1.f) * 0.5f : 0.f;
                v2 = (s0g + 2 < t) ? (acc[2] + 1.f) * 0.5f : 0.f;
                v3 = (s0g + 3 < t) ? (acc[3] + 1.f) * 0.5f : 0.f;
            }
            vv[j][0] = v0; vv[j][1] = v1; vv[j][2] = v2; vv[j][3] = v3;
            float ts = (v0 + v1) + (v2 + v3);
            float q0 = __shfl(ts, tl);
            float q1 = __shfl(ts, tl + 16);
            float q2 = __shfl(ts, tl + 32);
            float q3 = __shfl(ts, tl + 48);
            tT[j] = (q0 + q1) + (q2 + q3);
            hq[j] = (quad < 1 ? q1 : 0.f) + (quad < 2 ? q2 : 0.f) +
                    (quad < 3 ? q3 : 0.f);
        }

        // ---- serial coupling: suffix of tile totals (4 adds) ----
        float d3 = hq[3] + run;
        float d2 = hq[2] + tT[3] + run;
        float d1 = hq[1] + (tT[2] + tT[3]) + run;
        float d0 = hq[0] + (tT[1] + (tT[2] + tT[3])) + run;
        run += (tT[0] + tT[1]) + (tT[2] + tT[3]);
        float dbase[4] = {d0, d1, d2, d3};

        // ---- phase B: weights (independent across tiles) ----
        #pragma unroll
        for (int j = 0; j < 4; j++) {
            const int i = sb * 4 + j;
            if (i < cnt) {
                const int s_base = (start + i) << 4;
                float v0 = vv[j][0], v1 = vv[j][1], v2 = vv[j][2], v3 = vv[j][3];
                float suf3 = v3;
                float suf2 = v2 + suf3;
                float suf1 = v1 + suf2;
                float suf0 = v0 + suf1;
                float db = dbase[j];
                float4 yv = ((const float4*)(yb + s_base))[quad];
                float w0 = v0 * __expf(-lam_t * (suf0 + db));
                float w1 = v1 * __expf(-lam_t * (suf1 + db));
                float w2 = v2 * __expf(-lam_t * (suf2 + db));
                float w3 = v3 * __expf(-lam_t * (suf3 + db));
                wsum += (w0 + w1) + (w2 + w3);
                wy   += w0 * yv.x + w1 * yv.y + w2 * yv.z + w3 * yv.w;
            }
        }
    }

    // reduce across quads for each t, store per-wave partials
    float Wt = __shfl(wsum, tl) + __shfl(wsum, tl + 16) +
               __shfl(wsum, tl + 32) + __shfl(wsum, tl + 48);
    float Yt = __shfl(wy, tl) + __shfl(wy, tl + 16) +
               __shfl(wy, tl + 32) + __shfl(wy, tl + 48);
    if (quad == 0) {
        Wc[wave][tl] = Wt;
        Yc[wave][tl] = Yt;
        Tc[wave][tl] = run;   // run is cross-quad complete & uniform
    }
    __syncthreads();

    // merge the 4 chunks (wave 3 = highest s, needs no rescale)
    if (tid < 16) {
        float lt = lam[rowbase + tt * 16 + tid];
        float A = 0.f, W = 0.f, Y = 0.f;
        #pragma unroll
        for (int c = 3; c >= 0; --c) {
            float sc = __expf(-lt * A);
            W += Wc[c][tid] * sc;
            Y += Yc[c][tid] * sc;
            A += Tc[c][tid];
        }
        float r = Y / (W + 1e-6f);
        out[rowbase + tt * 16 + tid] = fminf(fmaxf(r, 0.01f), 0.99f);
    }
}

extern "C" void kernel_launch(void* const* d_in, const int* in_sizes, int n_in,
                              void* d_out, int out_size, void* d_ws, size_t ws_size,
                              hipStream_t stream) {
    const float* y     = (const float*)d_in[0];
    const int*   seq   = (const int*)  d_in[1];
    const float* embd  = (const float*)d_in[2];
    const float* lam_w = (const float*)d_in[3];
    const float* lam_b = (const float*)d_in[4];
    float* out = (float*)d_out;

    unsigned short* xbf = (unsigned short*)d_ws;            // B*T*H bf16 = 8 MB
    float* lam = (float*)(xbf + (size_t)BB * TT * HH);      // B*T floats

    gather_norm<<<BB * TT / 8, 256, 0, stream>>>(seq, embd, lam_w, lam_b, xbf, lam);
    sim_kernel<<<BB * 64, 256, 0, stream>>>(xbf, lam, y, out);
}